// Round 6
// baseline (481.834 us; speedup 1.0000x reference)
//
#include <hip/hip_runtime.h>
#include <stdint.h>

typedef _Float16 f16;
typedef __attribute__((ext_vector_type(8))) _Float16 f16x8;
typedef __attribute__((ext_vector_type(4))) _Float16 f16x4;
typedef __attribute__((ext_vector_type(4))) float f32x4;

#define DEV static __device__ __forceinline__

DEV float siluf(float x){ return x/(1.f+expf(-x)); }

DEV void load_lds16(const f16* g, f16* l){
  __builtin_amdgcn_global_load_lds(
      (const __attribute__((address_space(1))) void*)g,
      (__attribute__((address_space(3))) void*)l, 16, 0, 0);
}

// ---------------------------------------------------------------------------
// Weight prep: fp32 -> fp16, transposed where GEMM needs B^T (N x K) layout.
// ---------------------------------------------------------------------------
__global__ __launch_bounds__(256)
void prep_kernel(const float* __restrict__ qkvw, const float* __restrict__ zw,
                 const float* __restrict__ opw, const float* __restrict__ sgw,
                 const float* __restrict__ suw, const float* __restrict__ sdw,
                 const float* __restrict__ guw, const float* __restrict__ dww,
                 f16* __restrict__ wqkvz, f16* __restrict__ wop, f16* __restrict__ wsgu,
                 f16* __restrict__ wsd, f16* __restrict__ wgu, f16* __restrict__ wdn)
{
  int b = blockIdx.x, tid = threadIdx.x;
  if (b >= 7168){
    if (b < 9216){
      size_t base = ((size_t)(b-7168))*4096 + (size_t)tid*16;
      long e = base>>20; long i = (base>>10)&1023; long d = base&1023;
      long ri = (i<512) ? ((i>>6)*128 + (i&63)) : (((i&511)>>6)*128 + 64 + (i&63));
      size_t dbase = ((size_t)e<<20) + ((size_t)ri<<10) + d;
      #pragma unroll
      for (int u=0;u<16;u++) wgu[dbase+u] = (f16)guw[base+u];
    } else {
      size_t base = ((size_t)(b-9216))*4096 + (size_t)tid*16;
      #pragma unroll
      for (int u=0;u<16;u++) wdn[base+u] = (f16)dww[base+u];
    }
    return;
  }
  const float* src; f16* dst; int N; int rowOff; int tile; int mode=0;
  if (b < 2048){ src=qkvw; dst=wqkvz; N=2048; rowOff=0;    tile=b; }
  else if (b < 3072){ src=zw;  dst=wqkvz; N=1024; rowOff=2048; tile=b-2048; }
  else if (b < 4096){ src=opw; dst=wop;  N=1024; rowOff=0;    tile=b-3072; }
  else if (b < 5120){ src=sgw; dst=wsgu; N=1024; rowOff=0;    tile=b-4096; mode=1; }
  else if (b < 6144){ src=suw; dst=wsgu; N=1024; rowOff=0;    tile=b-5120; mode=2; }
  else              { src=sdw; dst=wsd;  N=1024; rowOff=0;    tile=b-6144; }
  __shared__ float t32[32][33];
  int ntiles = N/32;
  int k0 = (tile/ntiles)*32, n0 = (tile%ntiles)*32;
  int rr = tid>>5, cc = tid&31;
  #pragma unroll
  for (int u=0;u<4;u++) t32[rr+u*8][cc] = src[(size_t)(k0+rr+u*8)*N + n0+cc];
  __syncthreads();
  #pragma unroll
  for (int u=0;u<4;u++){
    int vr = n0 + rr + u*8;
    int drow = rowOff + vr;
    if (mode==1) drow = (vr>>6)*128 + (vr&63);
    else if (mode==2) drow = (vr>>6)*128 + 64 + (vr&63);
    dst[(size_t)drow*1024 + k0+cc] = (f16)t32[cc][rr+u*8];
  }
}

// ---------------------------------------------------------------------------
// RMSNorm 1
// ---------------------------------------------------------------------------
__global__ __launch_bounds__(256)
void rms1(const float* __restrict__ xin, const float* __restrict__ w, f16* __restrict__ hb)
{
  __shared__ float red[4];
  int t = blockIdx.x, tid = threadIdx.x;
  const float* row = xin + (long)t*1024;
  float vals[4]; float ss=0.f;
  #pragma unroll
  for (int u=0;u<4;u++){ vals[u]=row[tid+256*u]; ss += vals[u]*vals[u]; }
  #pragma unroll
  for (int m=1;m<64;m<<=1) ss += __shfl_xor(ss,m);
  if ((tid&63)==0) red[tid>>6]=ss;
  __syncthreads();
  float sc = rsqrtf((red[0]+red[1]+red[2]+red[3])*(1.f/1024.f) + 1e-6f);
  #pragma unroll
  for (int u=0;u<4;u++){
    int d = tid+256*u;
    hb[(long)t*1024+d] = (f16)(vals[u]*sc*(1.f+w[d]));
  }
}

// ---------------------------------------------------------------------------
// RMSNorm 2 fused with router logits + top-2 (no global atomics).
// ---------------------------------------------------------------------------
__global__ __launch_bounds__(256)
void rms2(const float* __restrict__ xin, const float* __restrict__ w,
          const float* __restrict__ rw, const float* __restrict__ seg,
          f16* __restrict__ hb, float4* __restrict__ tkbuf, float* __restrict__ sig)
{
  __shared__ float red[4];
  __shared__ float rbuf[9][4];
  int t = blockIdx.x, tid = threadIdx.x, lane = tid&63, wv = tid>>6;
  const float* row = xin + (long)t*1024;
  float vals[4]; float ss=0.f;
  #pragma unroll
  for (int u=0;u<4;u++){ vals[u]=row[tid+256*u]; ss += vals[u]*vals[u]; }
  #pragma unroll
  for (int m=1;m<64;m<<=1) ss += __shfl_xor(ss,m);
  if (lane==0) red[wv]=ss;
  __syncthreads();
  float sc = rsqrtf((red[0]+red[1]+red[2]+red[3])*(1.f/1024.f) + 1e-6f);
  float p[9];
  #pragma unroll
  for (int e=0;e<9;e++) p[e]=0.f;
  #pragma unroll
  for (int u=0;u<4;u++){
    int d = tid+256*u;
    float v = vals[u]*sc*(1.f+w[d]);
    hb[(long)t*1024+d] = (f16)v;
    #pragma unroll
    for (int e=0;e<8;e++) p[e] += v*rw[e*1024+d];
    p[8] += v*seg[d];
  }
  #pragma unroll
  for (int e=0;e<9;e++)
    #pragma unroll
    for (int m=1;m<64;m<<=1) p[e] += __shfl_xor(p[e], m);
  if (lane==0){
    #pragma unroll
    for (int e=0;e<9;e++) rbuf[e][wv]=p[e];
  }
  __syncthreads();
  if (tid==0){
    float pl[9];
    #pragma unroll
    for (int e=0;e<9;e++) pl[e]=rbuf[e][0]+rbuf[e][1]+rbuf[e][2]+rbuf[e][3];
    float mx = pl[0];
    for (int e=1;e<8;e++) mx = fmaxf(mx,pl[e]);
    float pe[8];
    for (int e=0;e<8;e++) pe[e]=expf(pl[e]-mx);
    int i0=0; for (int e=1;e<8;e++) if (pe[e]>pe[i0]) i0=e;
    int i1 = (i0==0)?1:0;
    for (int e=0;e<8;e++) if (e!=i0 && pe[e]>pe[i1]) i1=e;
    float denom = pe[i0]+pe[i1];
    float4 outp;
    outp.x = __int_as_float(i0);
    outp.y = __int_as_float(i1);
    outp.z = pe[i0]/denom;
    outp.w = pe[i1]/denom;
    tkbuf[t] = outp;
    sig[t] = 1.f/(1.f+expf(-pl[8]));
  }
}

// ---------------------------------------------------------------------------
// Single-workgroup token-list build (LDS atomics).
// ---------------------------------------------------------------------------
__global__ __launch_bounds__(1024)
void route_build(const float4* __restrict__ tkbuf,
                 int* __restrict__ cnt, int* __restrict__ etok,
                 int* __restrict__ eslot, float* __restrict__ ew)
{
  __shared__ int lcnt[8];
  int tid = threadIdx.x;
  if (tid<8) lcnt[tid]=0;
  __syncthreads();
  #pragma unroll
  for (int u=0;u<2;u++){
    int t = tid + u*1024;
    float4 pk = tkbuf[t];
    int i0 = __float_as_int(pk.x), i1 = __float_as_int(pk.y);
    int p0 = atomicAdd(&lcnt[i0],1);
    etok[i0*2048+p0]=t; eslot[i0*2048+p0]=0; ew[i0*2048+p0]=pk.z;
    int p1 = atomicAdd(&lcnt[i1],1);
    etok[i1*2048+p1]=t; eslot[i1*2048+p1]=1; ew[i1*2048+p1]=pk.w;
  }
  __syncthreads();
  if (tid<8) cnt[tid]=lcnt[tid];
}

// ---------------------------------------------------------------------------
// Generic 128x128 fp16 MFMA GEMM, BK=64, 4 waves, global_load_lds staging.
// ---------------------------------------------------------------------------
constexpr int GM_PLAIN16=0, GM_ADDX=1, GM_GUF=2, GM_DOWN=3, GM_SHD=4, GM_SGUF=5;

template<int MODE>
__global__ __launch_bounds__(256)
void gemm_k(const f16* __restrict__ A, long strideA,
            const f16* __restrict__ B, long strideB,
            int K, int lda, int ldb,
            float* __restrict__ Cf, f16* __restrict__ Cb, int ldc, long strideCb,
            const float* __restrict__ xadd,
            const int* __restrict__ tok, const int* __restrict__ cntp,
            const int* __restrict__ slot, const float* __restrict__ wgt,
            const float* __restrict__ sig)
{
  constexpr bool FUSED = (MODE==GM_GUF || MODE==GM_SGUF);
  __shared__ f16 As[128*64];
  __shared__ f16 Bs[128*64];
  __shared__ int ltok[128];
  const int e = blockIdx.z;
  const int m0 = blockIdx.y*128, n0 = blockIdx.x*128;
  int cnt = 0x7fffffff;
  if (MODE==GM_GUF || MODE==GM_DOWN){
    cnt = cntp[e];
    if (m0 >= cnt) return;
  }
  const f16* Ap = A + (long)e*strideA;
  const f16* Bp = B + (long)e*strideB;
  const int tid = threadIdx.x, lane = tid&63, wv = tid>>6;
  if (MODE==GM_GUF){
    if (tid < 128){
      int p = m0 + tid;
      ltok[tid] = (p < cnt) ? tok[e*2048 + p] : 0;
    }
    __syncthreads();
  }
  const int srow = wv*8 + (lane>>3);
  const int scol = (lane&7)*8;
  long arow[4];
  #pragma unroll
  for (int i=0;i<4;i++){
    int r = srow + i*32;
    arow[i] = (MODE==GM_GUF) ? (long)ltok[r] : (long)(m0 + r);
  }
  f32x4 acc[4][4];
  #pragma unroll
  for (int mi=0;mi<4;mi++)
    #pragma unroll
    for (int ni=0;ni<4;ni++)
      acc[mi][ni] = (f32x4){0.f,0.f,0.f,0.f};

  for (int k0=0;k0<K;k0+=64){
    __syncthreads();
    #pragma unroll
    for (int i=0;i<4;i++){
      int r = srow + i*32;
      load_lds16(Ap + arow[i]*lda + k0 + scol, &As[r*64 + scol]);
      load_lds16(Bp + (long)(n0 + r)*ldb + k0 + scol, &Bs[r*64 + scol]);
    }
    __syncthreads();
    #pragma unroll
    for (int kk=0;kk<64;kk+=32){
      f16x8 af[4], bf[4];
      #pragma unroll
      for (int mi=0;mi<4;mi++){
        int row = (wv&1)*64 + mi*16 + (lane&15);
        af[mi] = *(const f16x8*)&As[row*64 + kk + (lane>>4)*8];
      }
      #pragma unroll
      for (int ni=0;ni<4;ni++){
        int row = FUSED ? (ni*32 + (wv>>1)*16 + (lane&15))
                        : ((wv>>1)*64 + ni*16 + (lane&15));
        bf[ni] = *(const f16x8*)&Bs[row*64 + kk + (lane>>4)*8];
      }
      #pragma unroll
      for (int mi=0;mi<4;mi++)
        #pragma unroll
        for (int ni=0;ni<4;ni++)
          acc[mi][ni] = __builtin_amdgcn_mfma_f32_16x16x32_f16(af[mi], bf[ni], acc[mi][ni], 0,0,0);
    }
  }
  if (FUSED){
    #pragma unroll
    for (int mi=0;mi<4;mi++){
      #pragma unroll
      for (int r=0;r<4;r++){
        int rowl = (wv&1)*64 + mi*16 + (lane>>4)*4 + r;
        int pos = m0 + rowl;
        #pragma unroll
        for (int pi=0;pi<2;pi++){
          int v = (n0>>1) + pi*32 + (wv>>1)*16 + (lane&15);
          float g = acc[mi][pi][r], u = acc[mi][pi+2][r];
          f16 a = (f16)(siluf(g)*u);
          if (MODE==GM_GUF) Cb[(long)e*strideCb + (long)pos*ldc + v] = a;
          else              Cb[(long)pos*ldc + v] = a;
        }
      }
    }
  } else {
    #pragma unroll
    for (int mi=0;mi<4;mi++){
      #pragma unroll
      for (int r=0;r<4;r++){
        int rowl = (wv&1)*64 + mi*16 + (lane>>4)*4 + r;
        int pos = m0 + rowl;
        int tk=0, sl=0; float wrow=0.f;
        if (MODE==GM_DOWN){
          if (pos < cnt){ tk = tok[e*2048+pos]; sl = slot[e*2048+pos]; wrow = wgt[e*2048+pos]; }
        }
        #pragma unroll
        for (int ni=0;ni<4;ni++){
          int col = n0 + (wv>>1)*64 + ni*16 + (lane&15);
          float v = acc[mi][ni][r];
          if (MODE==GM_PLAIN16){
            Cb[(long)pos*ldc + col] = (f16)v;
          } else if (MODE==GM_ADDX){
            long idx = (long)pos*ldc + col;
            Cf[idx] = v + xadd[idx];
          } else if (MODE==GM_DOWN){
            if (pos < cnt) Cf[(long)sl*2097152 + (long)tk*1024 + col] = v*wrow;
          } else {
            Cf[(long)pos*ldc + col] = v*sig[pos];
          }
        }
      }
    }
  }
}

// ---------------------------------------------------------------------------
// a/b projections + gates
// ---------------------------------------------------------------------------
__global__ __launch_bounds__(256)
void ab_kernel(const f16* __restrict__ hb, const float* __restrict__ Wa,
               const float* __restrict__ Wbp, const float* __restrict__ dtb,
               const float* __restrict__ alog,
               float* __restrict__ gg, float* __restrict__ bbet)
{
  __shared__ float hrow[1024];
  __shared__ float part[256];
  int t = blockIdx.x, tid = threadIdx.x;
  #pragma unroll
  for (int u=0;u<4;u++){ int d = tid+256*u; hrow[d] = (float)hb[(long)t*1024+d]; }
  __syncthreads();
  int o = tid & 31;
  int r = tid >> 5;
  const float* W = (o<16) ? Wa : Wbp;
  int col = o & 15;
  float s = 0.f;
  for (int d=r; d<1024; d+=8) s += hrow[d]*W[d*16+col];
  part[tid] = s;
  __syncthreads();
  if (tid < 32){
    float tot=0.f;
    #pragma unroll
    for (int q=0;q<8;q++) tot += part[q*32 + tid];
    if (tid<16){
      float a = tot + dtb[tid];
      float sp = (a>20.f)? a : log1pf(expf(a));
      gg[t*16+tid] = -expf(alog[tid])*sp;
    } else {
      bbet[t*16+(tid-16)] = 1.f/(1.f+expf(-tot));
    }
  }
}

// ---------------------------------------------------------------------------
// Depthwise conv(KW=4) + SiLU + split + l2norm(q,k); q/k/v now f16 out.
// ---------------------------------------------------------------------------
__global__ __launch_bounds__(256)
void conv_kernel(const f16* __restrict__ qkvz, const float* __restrict__ cs,
                 const float* __restrict__ cw,
                 f16* __restrict__ qn, f16* __restrict__ kn,
                 f16* __restrict__ vb, float* __restrict__ conv_out)
{
  int t = blockIdx.y;
  int c = blockIdx.x*256 + threadIdx.x;
  f32x4 w4 = *(const f32x4*)&cw[c*4];
  float acc = 0.f;
  #pragma unroll
  for (int j=0;j<4;j++){
    int s = t + j;
    float xv = (s<3) ? cs[s*2048 + c] : (float)qkvz[(long)(s-3)*3072 + c];
    acc += w4[j]*xv;
  }
  float sv = siluf(acc);
  if (c < 1024){
    float ssq = sv*sv;
    #pragma unroll
    for (int m=1;m<64;m<<=1) ssq += __shfl_xor(ssq, m);
    float y = sv*rsqrtf(ssq + 1e-6f);
    if (c < 512) qn[(long)t*512 + c] = (f16)(y*0.125f);
    else         kn[(long)t*512 + (c-512)] = (f16)y;
  } else {
    vb[(long)t*1024 + (c-1024)] = (f16)sv;
  }
  if (t >= 2045) conv_out[(t-2045)*2048 + c] = (float)qkvz[(long)t*3072 + c];
}

// ---------------------------------------------------------------------------
// Chunked delta-rule precompute, MFMA; all intermediates f16 out.
// ---------------------------------------------------------------------------
__global__ __launch_bounds__(256)
void scan_pre(const f16* __restrict__ kn, const f16* __restrict__ vg,
              const float* __restrict__ gg, const float* __restrict__ bb,
              f16* __restrict__ U0, f16* __restrict__ WbB,
              f16* __restrict__ MT, f16* __restrict__ NT)
{
  __shared__ f16 Kh[64][72];
  __shared__ f16 KrT[64][72];
  __shared__ f16 Amh[64][72];
  __shared__ float XT[64][68];
  __shared__ f16 Xh[64][72];
  __shared__ float cexp[64], gam[64], rlast[64], betl[64];
  const int task = blockIdx.x;
  const int h = task>>5, c = task&31, hk = h>>1;
  const int tid = threadIdx.x, lane = tid&63, wv = tid>>6;
  const long tb = (long)task*4096;

  if (wv==0){
    float g = gg[(c*64+lane)*16 + h];
    #pragma unroll
    for (int off=1; off<64; off<<=1){
      float tpp = __shfl_up(g, off);
      if (lane >= off) g += tpp;
    }
    cexp[lane] = g;
    betl[lane] = bb[(c*64+lane)*16 + h];
  }
  __syncthreads();
  if (tid<64){ gam[tid]=expf(cexp[tid]); rlast[tid]=expf(cexp[63]-cexp[tid]); }
  __syncthreads();
  for (int u=0;u<16;u++){
    int e2=u*256+tid; int t=e2>>6, x=e2&63;
    f16 kx = kn[(long)(c*64+t)*512 + hk*64 + x];
    Kh[t][x] = kx;
    KrT[x][t] = (f16)(rlast[t]*(float)kx);
  }
  __syncthreads();
  {
    int mt = wv;
    for (int nt=0;nt<4;nt++){
      f32x4 acc = {0.f,0.f,0.f,0.f};
      #pragma unroll
      for (int kk=0;kk<64;kk+=32){
        f16x8 a = *(const f16x8*)&Kh[mt*16 + (lane&15)][kk + (lane>>4)*8];
        f16x8 bB = *(const f16x8*)&Kh[nt*16 + (lane&15)][kk + (lane>>4)*8];
        acc = __builtin_amdgcn_mfma_f32_16x16x32_f16(a, bB, acc, 0,0,0);
      }
      #pragma unroll
      for (int r=0;r<4;r++){
        int t = mt*16 + (lane>>4)*4 + r;
        int i = nt*16 + (lane&15);
        float v = (i<t) ? betl[t]*expf(cexp[t]-cexp[i])*acc[r] : 0.f;
        Amh[t][i] = (f16)v;
      }
    }
  }

  for (int pass=0; pass<2; pass++){
    for (int u=0;u<18;u++) ((f16*)Xh)[u*256+tid] = (f16)0.f;
    for (int u=0;u<16;u++){
      int e2=u*256+tid; int t=e2>>6, col=e2&63;
      float v = (pass==0) ? betl[t]*(float)vg[(long)(c*64+t)*1024 + h*64 + col]
                          : betl[t]*gam[t]*(float)kn[(long)(c*64+t)*512 + hk*64 + col];
      XT[col][t] = v;
    }
    __syncthreads();

    for (int b4=0;b4<4;b4++){
      if (tid<64){
        int col = tid;
        float xr[16];
        #pragma unroll
        for (int j=0;j<16;j+=4){
          f32x4 v = *(const f32x4*)&XT[col][b4*16+j];
          xr[j]=v.x; xr[j+1]=v.y; xr[j+2]=v.z; xr[j+3]=v.w;
        }
        #pragma unroll
        for (int t=1;t<16;t++){
          float a = xr[t];
          #pragma unroll
          for (int i=0;i<t;i++) a -= (float)Amh[b4*16+t][b4*16+i]*xr[i];
          xr[t] = a;
        }
        #pragma unroll
        for (int j=0;j<16;j+=4)
          *(f32x4*)&XT[col][b4*16+j] = (f32x4){xr[j],xr[j+1],xr[j+2],xr[j+3]};
        f16x8 h0, h1;
        #pragma unroll
        for (int j=0;j<8;j++){ h0[j]=(f16)xr[j]; h1[j]=(f16)xr[8+j]; }
        *(f16x8*)&Xh[col][b4*16]   = h0;
        *(f16x8*)&Xh[col][b4*16+8] = h1;
        if (pass==0){
          #pragma unroll
          for (int j=0;j<16;j++) U0[tb + (b4*16+j)*64 + col] = (f16)xr[j];
        } else {
          #pragma unroll
          for (int j=0;j<16;j++) WbB[tb + (b4*16+j)*64 + col] = (f16)xr[j];
        }
      }
      __syncthreads();
      if (b4<3){
        int ntiles = 4*(3-b4);
        for (int idx=wv; idx<ntiles; idx+=4){
          int mtile = idx & 3;
          int ntile = idx >> 2;
          int tp0 = 16*(b4+1) + ntile*16;
          f16x8 a  = *(const f16x8*)&Xh[mtile*16 + (lane&15)][b4*16 + (lane>>4)*8];
          f16x8 bB = *(const f16x8*)&Amh[tp0 + (lane&15)][b4*16 + (lane>>4)*8];
          f32x4 acc = {0.f,0.f,0.f,0.f};
          acc = __builtin_amdgcn_mfma_f32_16x16x32_f16(a, bB, acc, 0,0,0);
          #pragma unroll
          for (int r=0;r<4;r++){
            int colr = mtile*16 + (lane>>4)*4 + r;
            int tp = tp0 + (lane&15);
            XT[colr][tp] -= acc[r];
          }
        }
      }
      __syncthreads();
    }
    for (int idx=wv; idx<16; idx+=4){
      int mtile = idx & 3, ntile = idx >> 2;
      f32x4 acc = {0.f,0.f,0.f,0.f};
      #pragma unroll
      for (int kk=0;kk<64;kk+=32){
        f16x8 a  = *(const f16x8*)&Xh[mtile*16 + (lane&15)][kk + (lane>>4)*8];
        f16x8 bB = *(const f16x8*)&KrT[ntile*16 + (lane&15)][kk + (lane>>4)*8];
        acc = __builtin_amdgcn_mfma_f32_16x16x32_f16(a, bB, acc, 0,0,0);
      }
      #pragma unroll
      for (int r=0;r<4;r++){
        int m = mtile*16 + (lane>>4)*4 + r;
        int n = ntile*16 + (lane&15);
        if (pass==0) NT[tb + m*64 + n] = (f16)acc[r];
        else         MT[tb + m*64 + n] = (f16)(((n==m)?gam[63]:0.f) - acc[r]);
      }
    }
    __syncthreads();
  }
}

// ---------------------------------------------------------------------------
// Sequential cross-chunk recurrence: S <- M_c S + N_c.
// M/N f16 in, SS f16 out. Block swizzle: same-head blocks share XCD L2
// (bid%8 identical for {h, h+16, h+32, h+48}).
// ---------------------------------------------------------------------------
__global__ __launch_bounds__(256)
void scan_seq(const float* __restrict__ st_in, const f16* __restrict__ MT,
              const f16* __restrict__ NT, f16* __restrict__ SS,
              float* __restrict__ st_out)
{
  __shared__ float Mb[2][64*64];
  __shared__ float Nb[2][16*64];
  __shared__ float Sl[64][16];
  const int h = blockIdx.x & 15, vgq = blockIdx.x >> 4;
  const int tid = threadIdx.x, lane = tid&63, wv = tid>>6;
  const long hb0 = (long)h*32*4096;
  {
    int kx = tid>>2, j0 = (tid&3)*4;
    f32x4 s = *(const f32x4*)&st_in[h*4096 + kx*64 + vgq*16 + j0];
    *(f32x4*)&Sl[kx][j0] = s;
  }
  f16x8 mh[2]; f16x4 nh;
  mh[0] = *(const f16x8*)&MT[hb0 + tid*16];
  mh[1] = *(const f16x8*)&MT[hb0 + tid*16 + 8];
  nh    = *(const f16x4*)&NT[hb0 + vgq*1024 + tid*4];
  #pragma unroll
  for (int v=0;v<2;v++)
    #pragma unroll
    for (int j=0;j<8;j++) Mb[0][tid*16 + v*8 + j] = (float)mh[v][j];
  #pragma unroll
  for (int j=0;j<4;j++) Nb[0][tid*4+j] = (float)nh[j];
  __syncthreads();

  const int kx = tid>>2, j0 = (tid&3)*4;
  for (int c=0;c<32;c++){
    const int buf = c&1;
    const long tb = hb0 + (long)c*4096;
    {
      f16x4 sso;
      f32x4 s = *(const f32x4*)&Sl[kx][j0];
      sso[0]=(f16)s.x; sso[1]=(f16)s.y; sso[2]=(f16)s.z; sso[3]=(f16)s.w;
      *(f16x4*)&SS[tb + kx*64 + vgq*16 + j0] = sso;
    }
    if (c<31){
      const long tb1 = tb + 4096;
      mh[0] = *(const f16x8*)&MT[tb1 + tid*16];
      mh[1] = *(const f16x8*)&MT[tb1 + tid*16 + 8];
      nh    = *(const f16x4*)&NT[tb1 + vgq*1024 + tid*4];
    }
    f32x4 acc = {0.f,0.f,0.f,0.f};
    #pragma unroll 16
    for (int b=0;b<64;b++){
      float m = Mb[buf][b*64 + lane];
      f32x4 s4 = *(const f32x4*)&Sl[b][wv*4];
      acc.x += m*s4.x; acc.y += m*s4.y; acc.z += m*s4.z; acc.w += m*s4.w;
    }
    __syncthreads();
    Sl[lane][wv*4+0] = acc.x + Nb[buf][(wv*4+0)*64 + lane];
    Sl[lane][wv*4+1] = acc.y + Nb[buf][(wv*4+1)*64 + lane];
    Sl[lane][wv*4+2] = acc.z + Nb[buf][(wv*4+2)*64 + lane];
    Sl[lane][wv*4+3] = acc.w + Nb[buf][(wv*4+3)*64 + lane];
    if (c<31){
      #pragma unroll
      for (int v=0;v<2;v++)
        #pragma unroll
        for (int j=0;j<8;j++) Mb[buf^1][tid*16 + v*8 + j] = (float)mh[v][j];
      #pragma unroll
      for (int j=0;j<4;j++) Nb[buf^1][tid*4+j] = (float)nh[j];
    }
    __syncthreads();
  }
  *(f32x4*)&st_out[h*4096 + kx*64 + vgq*16 + j0] = *(const f32x4*)&Sl[kx][j0];
}

// ---------------------------------------------------------------------------
// Chunk-parallel output, MFMA. All scan inputs f16.
// ---------------------------------------------------------------------------
__global__ __launch_bounds__(256)
void scan_out(const f16* __restrict__ qn, const f16* __restrict__ kn,
              const float* __restrict__ gg, const f16* __restrict__ U0,
              const f16* __restrict__ WbB, const f16* __restrict__ SS,
              const f16* __restrict__ qkvz, const float* __restrict__ nw,
              f16* __restrict__ obuf)
{
  __shared__ f16 Kh[64][72];
  __shared__ f16 Qh[64][72];
  __shared__ f16 Wbh[64][72];
  __shared__ f16 Bmh[64][72];
  __shared__ f16 STh[64][72];
  __shared__ f16 UTh[64][72];
  __shared__ float cexp[64], gam[64];
  const int task = blockIdx.x;
  const int h = task>>5, c = task&31, hk = h>>1;
  const int tid = threadIdx.x, lane = tid&63, wv = tid>>6;
  const long tb = (long)task*4096;

  if (wv==0){
    float g = gg[(c*64+lane)*16 + h];
    #pragma unroll
    for (int off=1; off<64; off<<=1){
      float tpp = __shfl_up(g, off);
      if (lane >= off) g += tpp;
    }
    cexp[lane]=g; gam[lane]=expf(g);
  }
  __syncthreads();
  for (int u=0;u<16;u++){
    int e2=u*256+tid; int t=e2>>6, x=e2&63;
    Kh[t][x] = kn[(long)(c*64+t)*512 + hk*64 + x];
    Qh[t][x] = qn[(long)(c*64+t)*512 + hk*64 + x];
    Wbh[t][x] = WbB[tb + t*64 + x];
    STh[x][t] = SS[tb + t*64 + x];
  }
  __syncthreads();
  {
    int mt = wv;
    for (int nt=0;nt<4;nt++){
      f32x4 acc={0.f,0.f,0.f,0.f};
      #pragma unroll
      for (int kk=0;kk<64;kk+=32){
        f16x8 a  = *(const f16x8*)&Qh[mt*16+(lane&15)][kk+(lane>>4)*8];
        f16x8 bB = *(const f16x8*)&Kh[nt*16+(lane&15)][kk+(lane>>4)*8];
        acc = __builtin_amdgcn_mfma_f32_16x16x32_f16(a,bB,acc,0,0,0);
      }
      #pragma unroll
      for (int r=0;r<4;r++){
        int t = mt*16+(lane>>4)*4+r;
        int i = nt*16+(lane&15);
        float v = (i<=t)? expf(cexp[t]-cexp[i])*acc[r] : 0.f;
        Bmh[t][i] = (f16)v;
      }
    }
  }
  __syncthreads();
  {
    int mt = wv;
    for (int nt=0;nt<4;nt++){
      f32x4 acc={0.f,0.f,0.f,0.f};
      #pragma unroll
      for (int kk=0;kk<64;kk+=32){
        f16x8 a  = *(const f16x8*)&Wbh[mt*16+(lane&15)][kk+(lane>>4)*8];
        f16x8 bB = *(const f16x8*)&STh[nt*16+(lane&15)][kk+(lane>>4)*8];
        acc = __builtin_amdgcn_mfma_f32_16x16x32_f16(a,bB,acc,0,0,0);
      }
      #pragma unroll
      for (int r=0;r<4;r++){
        int t = mt*16+(lane>>4)*4+r;
        int v = nt*16+(lane&15);
        float uv = (float)U0[tb + t*64 + v] - acc[r];
        UTh[v][t] = (f16)uv;
      }
    }
    for (int u=0;u<16;u++){
      int e2=u*256+tid; int t=e2>>6, x=e2&63;
      Qh[t][x] = (f16)(gam[t]*(float)Qh[t][x]);
    }
  }
  __syncthreads();
  {
    int mt = wv;
    f32x4 acc[4];
    for (int nt=0;nt<4;nt++){
      acc[nt]=(f32x4){0.f,0.f,0.f,0.f};
      #pragma unroll
      for (int kk=0;kk<64;kk+=32){
        f16x8 a  = *(const f16x8*)&Qh[mt*16+(lane&15)][kk+(lane>>4)*8];
        f16x8 bB = *(const f16x8*)&STh[nt*16+(lane&15)][kk+(lane>>4)*8];
        acc[nt] = __builtin_amdgcn_mfma_f32_16x16x32_f16(a,bB,acc[nt],0,0,0);
      }
      #pragma unroll
      for (int kk=0;kk<64;kk+=32){
        f16x8 a  = *(const f16x8*)&Bmh[mt*16+(lane&15)][kk+(lane>>4)*8];
        f16x8 bB = *(const f16x8*)&UTh[nt*16+(lane&15)][kk+(lane>>4)*8];
        acc[nt] = __builtin_amdgcn_mfma_f32_16x16x32_f16(a,bB,acc[nt],0,0,0);
      }
    }
    #pragma unroll
    for (int r=0;r<4;r++){
      float ss = acc[0][r]*acc[0][r] + acc[1][r]*acc[1][r]
               + acc[2][r]*acc[2][r] + acc[3][r]*acc[3][r];
      ss += __shfl_xor(ss,1); ss += __shfl_xor(ss,2);
      ss += __shfl_xor(ss,4); ss += __shfl_xor(ss,8);
      float scale = rsqrtf(ss*(1.f/64.f) + 1e-6f);
      int t = mt*16 + (lane>>4)*4 + r;
      int tg = c*64 + t;
      #pragma unroll
      for (int nt=0;nt<4;nt++){
        int v = nt*16 + (lane&15);
        float z = (float)qkvz[(long)tg*3072 + 2048 + h*64 + v];
        float val = acc[nt][r]*scale*(1.f+nw[h*64+v])*siluf(z);
        obuf[(long)tg*1024 + h*64 + v] = (f16)val;
      }
    }
  }
}

__global__ __launch_bounds__(256)
void fin_kernel(const float* __restrict__ x2, const float* __restrict__ eo2,
                const float* __restrict__ sh, float* __restrict__ outx)
{
  long idx = (long)blockIdx.x*256 + threadIdx.x;
  outx[idx] = x2[idx] + eo2[idx] + eo2[idx + 2097152] + sh[idx];
}

// ---------------------------------------------------------------------------
extern "C" void kernel_launch(void* const* d_in, const int* in_sizes, int n_in,
                              void* d_out, int out_size, void* d_ws, size_t ws_size,
                              hipStream_t stream)
{
  (void)in_sizes; (void)n_in; (void)out_size; (void)ws_size;
  const float* x      = (const float*)d_in[0];
  const float* state  = (const float*)d_in[1];
  const float* cstate = (const float*)d_in[2];
  const float* w_qkv  = (const float*)d_in[3];
  const float* w_z    = (const float*)d_in[4];
  const float* w_a    = (const float*)d_in[5];
  const float* w_b    = (const float*)d_in[6];
  const float* convw  = (const float*)d_in[7];
  const float* dtb    = (const float*)d_in[8];
  const float* alog   = (const float*)d_in[9];
  const float* normw  = (const float*)d_in[10];
  const float* w_op   = (const float*)d_in[11];
  const float* rw     = (const float*)d_in[12];
  const float* w_gu   = (const float*)d_in[13];
  const float* w_dn   = (const float*)d_in[14];
  const float* w_sg   = (const float*)d_in[15];
  const float* w_su   = (const float*)d_in[16];
  const float* w_sd   = (const float*)d_in[17];
  const float* w_seg  = (const float*)d_in[18];
  const float* anw    = (const float*)d_in[19];
  const float* fnw    = (const float*)d_in[20];

  char* ws = (char*)d_ws;
  size_t off = 0;
  auto alloc = [&](size_t bytes)->char*{
    char* p = ws + off; off += (bytes + 255) & ~(size_t)255; return p;
  };
  f16*  wTqkvz = (f16*)alloc((size_t)3072*1024*2);
  f16*  wTop   = (f16*)alloc((size_t)1024*1024*2);
  f16*  wTsgu  = (f16*)alloc((size_t)2048*1024*2);
  f16*  wTsd   = (f16*)alloc((size_t)1024*1024*2);
  f16*  wGUc   = (f16*)alloc((size_t)8*1024*1024*2);
  f16*  wDNc   = (f16*)alloc((size_t)8*1024*512*2);
  f16*  hbuf   = (f16*)alloc((size_t)2048*1024*2);
  f16*  qkvzh  = (f16*)alloc((size_t)2048*3072*2);
  f16*  qn     = (f16*)alloc((size_t)2048*512*2);
  f16*  kn     = (f16*)alloc((size_t)2048*512*2);
  f16*  vb     = (f16*)alloc((size_t)2048*1024*2);
  float* gg    = (float*)alloc((size_t)2048*16*4);
  float* bbuf  = (float*)alloc((size_t)2048*16*4);
  f16*  U0     = (f16*)alloc((size_t)512*4096*2);   // scan block: 16MB contiguous f16
  f16*  WbB    = (f16*)alloc((size_t)512*4096*2);
  f16*  MT     = (f16*)alloc((size_t)512*4096*2);
  f16*  NT     = (f16*)alloc((size_t)512*4096*2);
  f16*  SS     = (f16*)alloc((size_t)512*4096*2);
  float* x2    = (float*)alloc((size_t)2048*1024*4);
  f16*  hfb    = (f16*)alloc((size_t)2048*1024*2);
  int*  cnt    = (int*)alloc(256);
  int*  etok   = (int*)alloc((size_t)8*2048*4);
  int*  eslot  = (int*)alloc((size_t)8*2048*4);
  float* ew    = (float*)alloc((size_t)8*2048*4);
  float* sigb  = (float*)alloc((size_t)2048*4);
  float4* tkbuf= (float4*)alloc((size_t)2048*16);
  float* eo2   = (float*)alloc((size_t)2*2048*1024*4);
  f16*  sactb  = (f16*)alloc((size_t)2048*1024*2);
  float* shb   = (float*)alloc((size_t)2048*1024*4);
  f16*  obuf  = hbuf;
  f16*  actb  = (f16*)U0;    // 16MB: U0+WbB+MT+NT (all dead before GUF)

  float* out_x = (float*)d_out;
  float* out_state = out_x + 2097152;
  float* out_conv = out_state + 65536;

  prep_kernel<<<10240, 256, 0, stream>>>(w_qkv, w_z, w_op, w_sg, w_su, w_sd, w_gu, w_dn,
                                         wTqkvz, wTop, wTsgu, wTsd, wGUc, wDNc);
  rms1<<<2048, 256, 0, stream>>>(x, anw, hbuf);
  gemm_k<GM_PLAIN16><<<dim3(24,16,1), 256, 0, stream>>>(hbuf, 0, wTqkvz, 0, 1024, 1024, 1024,
        nullptr, qkvzh, 3072, 0, nullptr, nullptr, nullptr, nullptr, nullptr, nullptr);
  ab_kernel<<<2048, 256, 0, stream>>>(hbuf, w_a, w_b, dtb, alog, gg, bbuf);
  conv_kernel<<<dim3(8,2048), 256, 0, stream>>>(qkvzh, cstate, convw, qn, kn, vb, out_conv);
  scan_pre<<<512, 256, 0, stream>>>(kn, vb, gg, bbuf, U0, WbB, MT, NT);
  scan_seq<<<64, 256, 0, stream>>>(state, MT, NT, SS, out_state);
  scan_out<<<512, 256, 0, stream>>>(qn, kn, gg, U0, WbB, SS, qkvzh, normw, obuf);
  gemm_k<GM_ADDX><<<dim3(8,16,1), 256, 0, stream>>>(obuf, 0, wTop, 0, 1024, 1024, 1024,
        x2, nullptr, 1024, 0, x, nullptr, nullptr, nullptr, nullptr, nullptr);
  rms2<<<2048, 256, 0, stream>>>(x2, fnw, rw, w_seg, hfb, tkbuf, sigb);
  route_build<<<1, 1024, 0, stream>>>(tkbuf, cnt, etok, eslot, ew);
  gemm_k<GM_GUF><<<dim3(8,16,8), 256, 0, stream>>>(hfb, 0, wGUc, (long)1024*1024, 1024, 1024, 1024,
        nullptr, actb, 512, (long)2048*512, nullptr, etok, cnt, nullptr, nullptr, nullptr);
  gemm_k<GM_DOWN><<<dim3(8,16,8), 256, 0, stream>>>(actb, (long)2048*512, wDNc, (long)1024*512,
        512, 512, 512,
        eo2, nullptr, 1024, 0, nullptr, etok, cnt, eslot, ew, nullptr);
  gemm_k<GM_SGUF><<<dim3(16,16,1), 256, 0, stream>>>(hfb, 0, wTsgu, 0, 1024, 1024, 1024,
        nullptr, sactb, 1024, 0, nullptr, nullptr, nullptr, nullptr, nullptr, nullptr);
  gemm_k<GM_SHD><<<dim3(8,16,1), 256, 0, stream>>>(sactb, 0, wTsd, 0, 1024, 1024, 1024,
        shb, nullptr, 1024, 0, nullptr, nullptr, nullptr, nullptr, nullptr, sigb);
  fin_kernel<<<8192, 256, 0, stream>>>(x2, eo2, shb, out_x);
}

// Round 7
// 436.730 us; speedup vs baseline: 1.1033x; 1.1033x over previous
//
#include <hip/hip_runtime.h>
#include <stdint.h>

typedef _Float16 f16;
typedef __attribute__((ext_vector_type(8))) _Float16 f16x8;
typedef __attribute__((ext_vector_type(4))) _Float16 f16x4;
typedef __attribute__((ext_vector_type(4))) float f32x4;

#define DEV static __device__ __forceinline__

DEV float siluf(float x){ return x/(1.f+expf(-x)); }

DEV void load_lds16(const f16* g, f16* l){
  __builtin_amdgcn_global_load_lds(
      (const __attribute__((address_space(1))) void*)g,
      (__attribute__((address_space(3))) void*)l, 16, 0, 0);
}

// ---------------------------------------------------------------------------
// Weight prep: fp32 -> fp16, transposed where GEMM needs B^T (N x K) layout.
// ---------------------------------------------------------------------------
__global__ __launch_bounds__(256)
void prep_kernel(const float* __restrict__ qkvw, const float* __restrict__ zw,
                 const float* __restrict__ opw, const float* __restrict__ sgw,
                 const float* __restrict__ suw, const float* __restrict__ sdw,
                 const float* __restrict__ guw, const float* __restrict__ dww,
                 f16* __restrict__ wqkvz, f16* __restrict__ wop, f16* __restrict__ wsgu,
                 f16* __restrict__ wsd, f16* __restrict__ wgu, f16* __restrict__ wdn)
{
  int b = blockIdx.x, tid = threadIdx.x;
  if (b >= 7168){
    if (b < 9216){
      size_t base = ((size_t)(b-7168))*4096 + (size_t)tid*16;
      long e = base>>20; long i = (base>>10)&1023; long d = base&1023;
      long ri = (i<512) ? ((i>>6)*128 + (i&63)) : (((i&511)>>6)*128 + 64 + (i&63));
      size_t dbase = ((size_t)e<<20) + ((size_t)ri<<10) + d;
      #pragma unroll
      for (int u=0;u<16;u++) wgu[dbase+u] = (f16)guw[base+u];
    } else {
      size_t base = ((size_t)(b-9216))*4096 + (size_t)tid*16;
      #pragma unroll
      for (int u=0;u<16;u++) wdn[base+u] = (f16)dww[base+u];
    }
    return;
  }
  const float* src; f16* dst; int N; int rowOff; int tile; int mode=0;
  if (b < 2048){ src=qkvw; dst=wqkvz; N=2048; rowOff=0;    tile=b; }
  else if (b < 3072){ src=zw;  dst=wqkvz; N=1024; rowOff=2048; tile=b-2048; }
  else if (b < 4096){ src=opw; dst=wop;  N=1024; rowOff=0;    tile=b-3072; }
  else if (b < 5120){ src=sgw; dst=wsgu; N=1024; rowOff=0;    tile=b-4096; mode=1; }
  else if (b < 6144){ src=suw; dst=wsgu; N=1024; rowOff=0;    tile=b-5120; mode=2; }
  else              { src=sdw; dst=wsd;  N=1024; rowOff=0;    tile=b-6144; }
  __shared__ float t32[32][33];
  int ntiles = N/32;
  int k0 = (tile/ntiles)*32, n0 = (tile%ntiles)*32;
  int rr = tid>>5, cc = tid&31;
  #pragma unroll
  for (int u=0;u<4;u++) t32[rr+u*8][cc] = src[(size_t)(k0+rr+u*8)*N + n0+cc];
  __syncthreads();
  #pragma unroll
  for (int u=0;u<4;u++){
    int vr = n0 + rr + u*8;
    int drow = rowOff + vr;
    if (mode==1) drow = (vr>>6)*128 + (vr&63);
    else if (mode==2) drow = (vr>>6)*128 + 64 + (vr&63);
    dst[(size_t)drow*1024 + k0+cc] = (f16)t32[cc][rr+u*8];
  }
}

// ---------------------------------------------------------------------------
// RMSNorm 1
// ---------------------------------------------------------------------------
__global__ __launch_bounds__(256)
void rms1(const float* __restrict__ xin, const float* __restrict__ w, f16* __restrict__ hb)
{
  __shared__ float red[4];
  int t = blockIdx.x, tid = threadIdx.x;
  const float* row = xin + (long)t*1024;
  float vals[4]; float ss=0.f;
  #pragma unroll
  for (int u=0;u<4;u++){ vals[u]=row[tid+256*u]; ss += vals[u]*vals[u]; }
  #pragma unroll
  for (int m=1;m<64;m<<=1) ss += __shfl_xor(ss,m);
  if ((tid&63)==0) red[tid>>6]=ss;
  __syncthreads();
  float sc = rsqrtf((red[0]+red[1]+red[2]+red[3])*(1.f/1024.f) + 1e-6f);
  #pragma unroll
  for (int u=0;u<4;u++){
    int d = tid+256*u;
    hb[(long)t*1024+d] = (f16)(vals[u]*sc*(1.f+w[d]));
  }
}

// ---------------------------------------------------------------------------
// RMSNorm 2 fused with router logits + top-2 (no global atomics).
// ---------------------------------------------------------------------------
__global__ __launch_bounds__(256)
void rms2(const float* __restrict__ xin, const float* __restrict__ w,
          const float* __restrict__ rw, const float* __restrict__ seg,
          f16* __restrict__ hb, float4* __restrict__ tkbuf, float* __restrict__ sig)
{
  __shared__ float red[4];
  __shared__ float rbuf[9][4];
  int t = blockIdx.x, tid = threadIdx.x, lane = tid&63, wv = tid>>6;
  const float* row = xin + (long)t*1024;
  float vals[4]; float ss=0.f;
  #pragma unroll
  for (int u=0;u<4;u++){ vals[u]=row[tid+256*u]; ss += vals[u]*vals[u]; }
  #pragma unroll
  for (int m=1;m<64;m<<=1) ss += __shfl_xor(ss,m);
  if (lane==0) red[wv]=ss;
  __syncthreads();
  float sc = rsqrtf((red[0]+red[1]+red[2]+red[3])*(1.f/1024.f) + 1e-6f);
  float p[9];
  #pragma unroll
  for (int e=0;e<9;e++) p[e]=0.f;
  #pragma unroll
  for (int u=0;u<4;u++){
    int d = tid+256*u;
    float v = vals[u]*sc*(1.f+w[d]);
    hb[(long)t*1024+d] = (f16)v;
    #pragma unroll
    for (int e=0;e<8;e++) p[e] += v*rw[e*1024+d];
    p[8] += v*seg[d];
  }
  #pragma unroll
  for (int e=0;e<9;e++)
    #pragma unroll
    for (int m=1;m<64;m<<=1) p[e] += __shfl_xor(p[e], m);
  if (lane==0){
    #pragma unroll
    for (int e=0;e<9;e++) rbuf[e][wv]=p[e];
  }
  __syncthreads();
  if (tid==0){
    float pl[9];
    #pragma unroll
    for (int e=0;e<9;e++) pl[e]=rbuf[e][0]+rbuf[e][1]+rbuf[e][2]+rbuf[e][3];
    float mx = pl[0];
    for (int e=1;e<8;e++) mx = fmaxf(mx,pl[e]);
    float pe[8];
    for (int e=0;e<8;e++) pe[e]=expf(pl[e]-mx);
    int i0=0; for (int e=1;e<8;e++) if (pe[e]>pe[i0]) i0=e;
    int i1 = (i0==0)?1:0;
    for (int e=0;e<8;e++) if (e!=i0 && pe[e]>pe[i1]) i1=e;
    float denom = pe[i0]+pe[i1];
    float4 outp;
    outp.x = __int_as_float(i0);
    outp.y = __int_as_float(i1);
    outp.z = pe[i0]/denom;
    outp.w = pe[i1]/denom;
    tkbuf[t] = outp;
    sig[t] = 1.f/(1.f+expf(-pl[8]));
  }
}

// ---------------------------------------------------------------------------
// Single-workgroup token-list build (LDS atomics).
// ---------------------------------------------------------------------------
__global__ __launch_bounds__(1024)
void route_build(const float4* __restrict__ tkbuf,
                 int* __restrict__ cnt, int* __restrict__ etok,
                 int* __restrict__ eslot, float* __restrict__ ew)
{
  __shared__ int lcnt[8];
  int tid = threadIdx.x;
  if (tid<8) lcnt[tid]=0;
  __syncthreads();
  #pragma unroll
  for (int u=0;u<2;u++){
    int t = tid + u*1024;
    float4 pk = tkbuf[t];
    int i0 = __float_as_int(pk.x), i1 = __float_as_int(pk.y);
    int p0 = atomicAdd(&lcnt[i0],1);
    etok[i0*2048+p0]=t; eslot[i0*2048+p0]=0; ew[i0*2048+p0]=pk.z;
    int p1 = atomicAdd(&lcnt[i1],1);
    etok[i1*2048+p1]=t; eslot[i1*2048+p1]=1; ew[i1*2048+p1]=pk.w;
  }
  __syncthreads();
  if (tid<8) cnt[tid]=lcnt[tid];
}

// ---------------------------------------------------------------------------
// Generic 128x128 fp16 MFMA GEMM, BK=64, 4 waves, global_load_lds staging.
// ---------------------------------------------------------------------------
constexpr int GM_PLAIN16=0, GM_ADDX=1, GM_GUF=2, GM_DOWN=3, GM_SHD=4, GM_SGUF=5;

template<int MODE>
__global__ __launch_bounds__(256)
void gemm_k(const f16* __restrict__ A, long strideA,
            const f16* __restrict__ B, long strideB,
            int K, int lda, int ldb,
            float* __restrict__ Cf, f16* __restrict__ Cb, int ldc, long strideCb,
            const float* __restrict__ xadd,
            const int* __restrict__ tok, const int* __restrict__ cntp,
            const int* __restrict__ slot, const float* __restrict__ wgt,
            const float* __restrict__ sig)
{
  constexpr bool FUSED = (MODE==GM_GUF || MODE==GM_SGUF);
  __shared__ f16 As[128*64];
  __shared__ f16 Bs[128*64];
  __shared__ int ltok[128];
  const int e = blockIdx.z;
  const int m0 = blockIdx.y*128, n0 = blockIdx.x*128;
  int cnt = 0x7fffffff;
  if (MODE==GM_GUF || MODE==GM_DOWN){
    cnt = cntp[e];
    if (m0 >= cnt) return;
  }
  const f16* Ap = A + (long)e*strideA;
  const f16* Bp = B + (long)e*strideB;
  const int tid = threadIdx.x, lane = tid&63, wv = tid>>6;
  if (MODE==GM_GUF){
    if (tid < 128){
      int p = m0 + tid;
      ltok[tid] = (p < cnt) ? tok[e*2048 + p] : 0;
    }
    __syncthreads();
  }
  const int srow = wv*8 + (lane>>3);
  const int scol = (lane&7)*8;
  long arow[4];
  #pragma unroll
  for (int i=0;i<4;i++){
    int r = srow + i*32;
    arow[i] = (MODE==GM_GUF) ? (long)ltok[r] : (long)(m0 + r);
  }
  f32x4 acc[4][4];
  #pragma unroll
  for (int mi=0;mi<4;mi++)
    #pragma unroll
    for (int ni=0;ni<4;ni++)
      acc[mi][ni] = (f32x4){0.f,0.f,0.f,0.f};

  for (int k0=0;k0<K;k0+=64){
    __syncthreads();
    #pragma unroll
    for (int i=0;i<4;i++){
      int r = srow + i*32;
      load_lds16(Ap + arow[i]*lda + k0 + scol, &As[r*64 + scol]);
      load_lds16(Bp + (long)(n0 + r)*ldb + k0 + scol, &Bs[r*64 + scol]);
    }
    __syncthreads();
    #pragma unroll
    for (int kk=0;kk<64;kk+=32){
      f16x8 af[4], bf[4];
      #pragma unroll
      for (int mi=0;mi<4;mi++){
        int row = (wv&1)*64 + mi*16 + (lane&15);
        af[mi] = *(const f16x8*)&As[row*64 + kk + (lane>>4)*8];
      }
      #pragma unroll
      for (int ni=0;ni<4;ni++){
        int row = FUSED ? (ni*32 + (wv>>1)*16 + (lane&15))
                        : ((wv>>1)*64 + ni*16 + (lane&15));
        bf[ni] = *(const f16x8*)&Bs[row*64 + kk + (lane>>4)*8];
      }
      #pragma unroll
      for (int mi=0;mi<4;mi++)
        #pragma unroll
        for (int ni=0;ni<4;ni++)
          acc[mi][ni] = __builtin_amdgcn_mfma_f32_16x16x32_f16(af[mi], bf[ni], acc[mi][ni], 0,0,0);
    }
  }
  if (FUSED){
    #pragma unroll
    for (int mi=0;mi<4;mi++){
      #pragma unroll
      for (int r=0;r<4;r++){
        int rowl = (wv&1)*64 + mi*16 + (lane>>4)*4 + r;
        int pos = m0 + rowl;
        #pragma unroll
        for (int pi=0;pi<2;pi++){
          int v = (n0>>1) + pi*32 + (wv>>1)*16 + (lane&15);
          float g = acc[mi][pi][r], u = acc[mi][pi+2][r];
          f16 a = (f16)(siluf(g)*u);
          if (MODE==GM_GUF) Cb[(long)e*strideCb + (long)pos*ldc + v] = a;
          else              Cb[(long)pos*ldc + v] = a;
        }
      }
    }
  } else {
    #pragma unroll
    for (int mi=0;mi<4;mi++){
      #pragma unroll
      for (int r=0;r<4;r++){
        int rowl = (wv&1)*64 + mi*16 + (lane>>4)*4 + r;
        int pos = m0 + rowl;
        int tk=0, sl=0; float wrow=0.f;
        if (MODE==GM_DOWN){
          if (pos < cnt){ tk = tok[e*2048+pos]; sl = slot[e*2048+pos]; wrow = wgt[e*2048+pos]; }
        }
        #pragma unroll
        for (int ni=0;ni<4;ni++){
          int col = n0 + (wv>>1)*64 + ni*16 + (lane&15);
          float v = acc[mi][ni][r];
          if (MODE==GM_PLAIN16){
            Cb[(long)pos*ldc + col] = (f16)v;
          } else if (MODE==GM_ADDX){
            long idx = (long)pos*ldc + col;
            Cf[idx] = v + xadd[idx];
          } else if (MODE==GM_DOWN){
            if (pos < cnt) Cf[(long)sl*2097152 + (long)tk*1024 + col] = v*wrow;
          } else {
            Cf[(long)pos*ldc + col] = v*sig[pos];
          }
        }
      }
    }
  }
}

// ---------------------------------------------------------------------------
// a/b projections + gates
// ---------------------------------------------------------------------------
__global__ __launch_bounds__(256)
void ab_kernel(const f16* __restrict__ hb, const float* __restrict__ Wa,
               const float* __restrict__ Wbp, const float* __restrict__ dtb,
               const float* __restrict__ alog,
               float* __restrict__ gg, float* __restrict__ bbet)
{
  __shared__ float hrow[1024];
  __shared__ float part[256];
  int t = blockIdx.x, tid = threadIdx.x;
  #pragma unroll
  for (int u=0;u<4;u++){ int d = tid+256*u; hrow[d] = (float)hb[(long)t*1024+d]; }
  __syncthreads();
  int o = tid & 31;
  int r = tid >> 5;
  const float* W = (o<16) ? Wa : Wbp;
  int col = o & 15;
  float s = 0.f;
  for (int d=r; d<1024; d+=8) s += hrow[d]*W[d*16+col];
  part[tid] = s;
  __syncthreads();
  if (tid < 32){
    float tot=0.f;
    #pragma unroll
    for (int q=0;q<8;q++) tot += part[q*32 + tid];
    if (tid<16){
      float a = tot + dtb[tid];
      float sp = (a>20.f)? a : log1pf(expf(a));
      gg[t*16+tid] = -expf(alog[tid])*sp;
    } else {
      bbet[t*16+(tid-16)] = 1.f/(1.f+expf(-tot));
    }
  }
}

// ---------------------------------------------------------------------------
// Depthwise conv(KW=4) + SiLU + split + l2norm(q,k); q/k/v f16 out.
// ---------------------------------------------------------------------------
__global__ __launch_bounds__(256)
void conv_kernel(const f16* __restrict__ qkvz, const float* __restrict__ cs,
                 const float* __restrict__ cw,
                 f16* __restrict__ qn, f16* __restrict__ kn,
                 f16* __restrict__ vb, float* __restrict__ conv_out)
{
  int t = blockIdx.y;
  int c = blockIdx.x*256 + threadIdx.x;
  f32x4 w4 = *(const f32x4*)&cw[c*4];
  float acc = 0.f;
  #pragma unroll
  for (int j=0;j<4;j++){
    int s = t + j;
    float xv = (s<3) ? cs[s*2048 + c] : (float)qkvz[(long)(s-3)*3072 + c];
    acc += w4[j]*xv;
  }
  float sv = siluf(acc);
  if (c < 1024){
    float ssq = sv*sv;
    #pragma unroll
    for (int m=1;m<64;m<<=1) ssq += __shfl_xor(ssq, m);
    float y = sv*rsqrtf(ssq + 1e-6f);
    if (c < 512) qn[(long)t*512 + c] = (f16)(y*0.125f);
    else         kn[(long)t*512 + (c-512)] = (f16)y;
  } else {
    vb[(long)t*1024 + (c-1024)] = (f16)sv;
  }
  if (t >= 2045) conv_out[(t-2045)*2048 + c] = (float)qkvz[(long)t*3072 + c];
}

// ---------------------------------------------------------------------------
// Chunked delta-rule precompute, MFMA; all intermediates f16.
// MT now stored [k'][b] (operand-swapped MFMA) for scan_seq's A operand.
// ---------------------------------------------------------------------------
__global__ __launch_bounds__(256)
void scan_pre(const f16* __restrict__ kn, const f16* __restrict__ vg,
              const float* __restrict__ gg, const float* __restrict__ bb,
              f16* __restrict__ U0, f16* __restrict__ WbB,
              f16* __restrict__ MT, f16* __restrict__ NT)
{
  __shared__ f16 Kh[64][72];
  __shared__ f16 KrT[64][72];
  __shared__ f16 Amh[64][72];
  __shared__ float XT[64][68];
  __shared__ f16 Xh[64][72];
  __shared__ float cexp[64], gam[64], rlast[64], betl[64];
  const int task = blockIdx.x;
  const int h = task>>5, c = task&31, hk = h>>1;
  const int tid = threadIdx.x, lane = tid&63, wv = tid>>6;
  const long tb = (long)task*4096;

  if (wv==0){
    float g = gg[(c*64+lane)*16 + h];
    #pragma unroll
    for (int off=1; off<64; off<<=1){
      float tpp = __shfl_up(g, off);
      if (lane >= off) g += tpp;
    }
    cexp[lane] = g;
    betl[lane] = bb[(c*64+lane)*16 + h];
  }
  __syncthreads();
  if (tid<64){ gam[tid]=expf(cexp[tid]); rlast[tid]=expf(cexp[63]-cexp[tid]); }
  __syncthreads();
  for (int u=0;u<16;u++){
    int e2=u*256+tid; int t=e2>>6, x=e2&63;
    f16 kx = kn[(long)(c*64+t)*512 + hk*64 + x];
    Kh[t][x] = kx;
    KrT[x][t] = (f16)(rlast[t]*(float)kx);
  }
  __syncthreads();
  {
    int mt = wv;
    for (int nt=0;nt<4;nt++){
      f32x4 acc = {0.f,0.f,0.f,0.f};
      #pragma unroll
      for (int kk=0;kk<64;kk+=32){
        f16x8 a = *(const f16x8*)&Kh[mt*16 + (lane&15)][kk + (lane>>4)*8];
        f16x8 bB = *(const f16x8*)&Kh[nt*16 + (lane&15)][kk + (lane>>4)*8];
        acc = __builtin_amdgcn_mfma_f32_16x16x32_f16(a, bB, acc, 0,0,0);
      }
      #pragma unroll
      for (int r=0;r<4;r++){
        int t = mt*16 + (lane>>4)*4 + r;
        int i = nt*16 + (lane&15);
        float v = (i<t) ? betl[t]*expf(cexp[t]-cexp[i])*acc[r] : 0.f;
        Amh[t][i] = (f16)v;
      }
    }
  }

  for (int pass=0; pass<2; pass++){
    for (int u=0;u<18;u++) ((f16*)Xh)[u*256+tid] = (f16)0.f;
    for (int u=0;u<16;u++){
      int e2=u*256+tid; int t=e2>>6, col=e2&63;
      float v = (pass==0) ? betl[t]*(float)vg[(long)(c*64+t)*1024 + h*64 + col]
                          : betl[t]*gam[t]*(float)kn[(long)(c*64+t)*512 + hk*64 + col];
      XT[col][t] = v;
    }
    __syncthreads();

    for (int b4=0;b4<4;b4++){
      if (tid<64){
        int col = tid;
        float xr[16];
        #pragma unroll
        for (int j=0;j<16;j+=4){
          f32x4 v = *(const f32x4*)&XT[col][b4*16+j];
          xr[j]=v.x; xr[j+1]=v.y; xr[j+2]=v.z; xr[j+3]=v.w;
        }
        #pragma unroll
        for (int t=1;t<16;t++){
          float a = xr[t];
          #pragma unroll
          for (int i=0;i<t;i++) a -= (float)Amh[b4*16+t][b4*16+i]*xr[i];
          xr[t] = a;
        }
        #pragma unroll
        for (int j=0;j<16;j+=4)
          *(f32x4*)&XT[col][b4*16+j] = (f32x4){xr[j],xr[j+1],xr[j+2],xr[j+3]};
        f16x8 h0, h1;
        #pragma unroll
        for (int j=0;j<8;j++){ h0[j]=(f16)xr[j]; h1[j]=(f16)xr[8+j]; }
        *(f16x8*)&Xh[col][b4*16]   = h0;
        *(f16x8*)&Xh[col][b4*16+8] = h1;
        if (pass==0){
          #pragma unroll
          for (int j=0;j<16;j++) U0[tb + (b4*16+j)*64 + col] = (f16)xr[j];
        } else {
          #pragma unroll
          for (int j=0;j<16;j++) WbB[tb + (b4*16+j)*64 + col] = (f16)xr[j];
        }
      }
      __syncthreads();
      if (b4<3){
        int ntiles = 4*(3-b4);
        for (int idx=wv; idx<ntiles; idx+=4){
          int mtile = idx & 3;
          int ntile = idx >> 2;
          int tp0 = 16*(b4+1) + ntile*16;
          f16x8 a  = *(const f16x8*)&Xh[mtile*16 + (lane&15)][b4*16 + (lane>>4)*8];
          f16x8 bB = *(const f16x8*)&Amh[tp0 + (lane&15)][b4*16 + (lane>>4)*8];
          f32x4 acc = {0.f,0.f,0.f,0.f};
          acc = __builtin_amdgcn_mfma_f32_16x16x32_f16(a, bB, acc, 0,0,0);
          #pragma unroll
          for (int r=0;r<4;r++){
            int colr = mtile*16 + (lane>>4)*4 + r;
            int tp = tp0 + (lane&15);
            XT[colr][tp] -= acc[r];
          }
        }
      }
      __syncthreads();
    }
    // NT (pass0): [v][k] as before. MT (pass1): operand-swapped -> [k'][b].
    for (int idx=wv; idx<16; idx+=4){
      int mtile = idx & 3, ntile = idx >> 2;
      f32x4 acc = {0.f,0.f,0.f,0.f};
      #pragma unroll
      for (int kk=0;kk<64;kk+=32){
        f16x8 fa, fb;
        if (pass==0){
          fa = *(const f16x8*)&Xh[mtile*16 + (lane&15)][kk + (lane>>4)*8];
          fb = *(const f16x8*)&KrT[ntile*16 + (lane&15)][kk + (lane>>4)*8];
        } else {
          fa = *(const f16x8*)&KrT[mtile*16 + (lane&15)][kk + (lane>>4)*8];
          fb = *(const f16x8*)&Xh[ntile*16 + (lane&15)][kk + (lane>>4)*8];
        }
        acc = __builtin_amdgcn_mfma_f32_16x16x32_f16(fa, fb, acc, 0,0,0);
      }
      #pragma unroll
      for (int r=0;r<4;r++){
        int m = mtile*16 + (lane>>4)*4 + r;
        int n = ntile*16 + (lane&15);
        if (pass==0) NT[tb + m*64 + n] = (f16)acc[r];
        else         MT[tb + m*64 + n] = (f16)(((n==m)?gam[63]:0.f) - acc[r]);
      }
    }
    __syncthreads();
  }
}

// ---------------------------------------------------------------------------
// Sequential cross-chunk recurrence, MFMA form: S <- M S + N per (head,
// v-slice). S kept as f16 S^T[v][k] in double-buffered LDS; M[k'][b] and
// N[v][k'] register-prefetched one chunk ahead. SS snapshot stored [v][k].
// ---------------------------------------------------------------------------
__global__ __launch_bounds__(256)
void scan_seq(const float* __restrict__ st_in, const f16* __restrict__ MT,
              const f16* __restrict__ NT, f16* __restrict__ SST,
              float* __restrict__ st_out)
{
  __shared__ f16 Ms[2][64*72];
  __shared__ f16 Nbuf[2][16*72];
  __shared__ f16 Sb[2][16*72];
  const int h = blockIdx.x & 15, vgq = blockIdx.x >> 4;
  const int tid = threadIdx.x, lane = tid&63, wv = tid>>6;
  const long hb0 = (long)h*32*4096;
  const int v0 = vgq*16;
  // init S^T slice from fp32 state
  {
    int vl = tid & 15, kb = (tid>>4)*4;
    f16x4 sv;
    #pragma unroll
    for (int j=0;j<4;j++) sv[j] = (f16)st_in[h*4096 + (kb+j)*64 + v0+vl];
    *(f16x4*)&Sb[0][vl*72 + kb] = sv;
  }
  // prefetch chunk 0
  f16x8 mreg0, mreg1; f16x4 nreg;
  mreg0 = *(const f16x8*)&MT[hb0 + tid*16];
  mreg1 = *(const f16x8*)&MT[hb0 + tid*16 + 8];
  nreg  = *(const f16x4*)&NT[hb0 + (v0 + (tid>>4))*64 + (tid&15)*4];
  {
    int row = tid>>2, col = (tid&3)*16;
    *(f16x8*)&Ms[0][row*72+col]   = mreg0;
    *(f16x8*)&Ms[0][row*72+col+8] = mreg1;
    *(f16x4*)&Nbuf[0][(tid>>4)*72 + (tid&15)*4] = nreg;
  }
  __syncthreads();

  const int m0 = wv*16;
  for (int c=0;c<32;c++){
    const int buf = c&1, nbuf = buf^1;
    const long tb = hb0 + (long)c*4096;
    // SS snapshot: S at entry of chunk c, [v][k] layout
    {
      int vl = tid>>4, kb = (tid&15)*4;
      f16x4 sv = *(const f16x4*)&Sb[buf][vl*72 + kb];
      *(f16x4*)&SST[tb + (v0+vl)*64 + kb] = sv;
    }
    // prefetch c+1 into registers
    if (c<31){
      const long cb = tb + 4096;
      mreg0 = *(const f16x8*)&MT[cb + tid*16];
      mreg1 = *(const f16x8*)&MT[cb + tid*16 + 8];
      nreg  = *(const f16x4*)&NT[cb + (v0 + (tid>>4))*64 + (tid&15)*4];
    }
    // S_new[k'][v] = sum_b M[k'][b] S[b][v] + N[k'][v], tile rows m0..m0+15
    f32x4 acc;
    {
      int v = lane&15, kq = m0 + (lane>>4)*4;
      f16x4 nv = *(const f16x4*)&Nbuf[buf][v*72 + kq];
      acc.x=(float)nv[0]; acc.y=(float)nv[1]; acc.z=(float)nv[2]; acc.w=(float)nv[3];
    }
    #pragma unroll
    for (int kk=0;kk<64;kk+=32){
      f16x8 a = *(const f16x8*)&Ms[buf][(m0+(lane&15))*72 + kk + (lane>>4)*8];
      f16x8 b = *(const f16x8*)&Sb[buf][(lane&15)*72 + kk + (lane>>4)*8];
      acc = __builtin_amdgcn_mfma_f32_16x16x32_f16(a, b, acc, 0,0,0);
    }
    // D -> next S^T (transpose write: [v][k'])
    {
      int v = lane&15, kq = m0 + (lane>>4)*4;
      f16x4 dv;
      dv[0]=(f16)acc.x; dv[1]=(f16)acc.y; dv[2]=(f16)acc.z; dv[3]=(f16)acc.w;
      *(f16x4*)&Sb[nbuf][v*72 + kq] = dv;
    }
    if (c<31){
      int row = tid>>2, col = (tid&3)*16;
      *(f16x8*)&Ms[nbuf][row*72+col]   = mreg0;
      *(f16x8*)&Ms[nbuf][row*72+col+8] = mreg1;
      *(f16x4*)&Nbuf[nbuf][(tid>>4)*72 + (tid&15)*4] = nreg;
    }
    __syncthreads();
  }
  // final state (fp32, [k][v])
  {
    int vl = tid & 15, kb = (tid>>4)*4;
    f16x4 sv = *(const f16x4*)&Sb[0][vl*72 + kb];
    #pragma unroll
    for (int j=0;j<4;j++) st_out[h*4096 + (kb+j)*64 + v0+vl] = (float)sv[j];
  }
}

// ---------------------------------------------------------------------------
// Chunk-parallel output, MFMA. SS now [v][k] -> conflict-free staging.
// ---------------------------------------------------------------------------
__global__ __launch_bounds__(256)
void scan_out(const f16* __restrict__ qn, const f16* __restrict__ kn,
              const float* __restrict__ gg, const f16* __restrict__ U0,
              const f16* __restrict__ WbB, const f16* __restrict__ SST,
              const f16* __restrict__ qkvz, const float* __restrict__ nw,
              f16* __restrict__ obuf)
{
  __shared__ f16 Kh[64][72];
  __shared__ f16 Qh[64][72];
  __shared__ f16 Wbh[64][72];
  __shared__ f16 Bmh[64][72];
  __shared__ f16 STh[64][72];
  __shared__ f16 UTh[64][72];
  __shared__ float cexp[64], gam[64];
  const int task = blockIdx.x;
  const int h = task>>5, c = task&31, hk = h>>1;
  const int tid = threadIdx.x, lane = tid&63, wv = tid>>6;
  const long tb = (long)task*4096;

  if (wv==0){
    float g = gg[(c*64+lane)*16 + h];
    #pragma unroll
    for (int off=1; off<64; off<<=1){
      float tpp = __shfl_up(g, off);
      if (lane >= off) g += tpp;
    }
    cexp[lane]=g; gam[lane]=expf(g);
  }
  __syncthreads();
  for (int u=0;u<16;u++){
    int e2=u*256+tid; int t=e2>>6, x=e2&63;
    Kh[t][x] = kn[(long)(c*64+t)*512 + hk*64 + x];
    Qh[t][x] = qn[(long)(c*64+t)*512 + hk*64 + x];
    Wbh[t][x] = WbB[tb + t*64 + x];
    STh[t][x] = SST[tb + t*64 + x];   // [v][k] layout, direct copy
  }
  __syncthreads();
  {
    int mt = wv;
    for (int nt=0;nt<4;nt++){
      f32x4 acc={0.f,0.f,0.f,0.f};
      #pragma unroll
      for (int kk=0;kk<64;kk+=32){
        f16x8 a  = *(const f16x8*)&Qh[mt*16+(lane&15)][kk+(lane>>4)*8];
        f16x8 bB = *(const f16x8*)&Kh[nt*16+(lane&15)][kk+(lane>>4)*8];
        acc = __builtin_amdgcn_mfma_f32_16x16x32_f16(a,bB,acc,0,0,0);
      }
      #pragma unroll
      for (int r=0;r<4;r++){
        int t = mt*16+(lane>>4)*4+r;
        int i = nt*16+(lane&15);
        float v = (i<=t)? expf(cexp[t]-cexp[i])*acc[r] : 0.f;
        Bmh[t][i] = (f16)v;
      }
    }
  }
  __syncthreads();
  {
    int mt = wv;
    for (int nt=0;nt<4;nt++){
      f32x4 acc={0.f,0.f,0.f,0.f};
      #pragma unroll
      for (int kk=0;kk<64;kk+=32){
        f16x8 a  = *(const f16x8*)&Wbh[mt*16+(lane&15)][kk+(lane>>4)*8];
        f16x8 bB = *(const f16x8*)&STh[nt*16+(lane&15)][kk+(lane>>4)*8];
        acc = __builtin_amdgcn_mfma_f32_16x16x32_f16(a,bB,acc,0,0,0);
      }
      #pragma unroll
      for (int r=0;r<4;r++){
        int t = mt*16+(lane>>4)*4+r;
        int v = nt*16+(lane&15);
        float uv = (float)U0[tb + t*64 + v] - acc[r];
        UTh[v][t] = (f16)uv;
      }
    }
    for (int u=0;u<16;u++){
      int e2=u*256+tid; int t=e2>>6, x=e2&63;
      Qh[t][x] = (f16)(gam[t]*(float)Qh[t][x]);
    }
  }
  __syncthreads();
  {
    int mt = wv;
    f32x4 acc[4];
    for (int nt=0;nt<4;nt++){
      acc[nt]=(f32x4){0.f,0.f,0.f,0.f};
      #pragma unroll
      for (int kk=0;kk<64;kk+=32){
        f16x8 a  = *(const f16x8*)&Qh[mt*16+(lane&15)][kk+(lane>>4)*8];
        f16x8 bB = *(const f16x8*)&STh[nt*16+(lane&15)][kk+(lane>>4)*8];
        acc[nt] = __builtin_amdgcn_mfma_f32_16x16x32_f16(a,bB,acc[nt],0,0,0);
      }
      #pragma unroll
      for (int kk=0;kk<64;kk+=32){
        f16x8 a  = *(const f16x8*)&Bmh[mt*16+(lane&15)][kk+(lane>>4)*8];
        f16x8 bB = *(const f16x8*)&UTh[nt*16+(lane&15)][kk+(lane>>4)*8];
        acc[nt] = __builtin_amdgcn_mfma_f32_16x16x32_f16(a,bB,acc[nt],0,0,0);
      }
    }
    #pragma unroll
    for (int r=0;r<4;r++){
      float ss = acc[0][r]*acc[0][r] + acc[1][r]*acc[1][r]
               + acc[2][r]*acc[2][r] + acc[3][r]*acc[3][r];
      ss += __shfl_xor(ss,1); ss += __shfl_xor(ss,2);
      ss += __shfl_xor(ss,4); ss += __shfl_xor(ss,8);
      float scale = rsqrtf(ss*(1.f/64.f) + 1e-6f);
      int t = mt*16 + (lane>>4)*4 + r;
      int tg = c*64 + t;
      #pragma unroll
      for (int nt=0;nt<4;nt++){
        int v = nt*16 + (lane&15);
        float z = (float)qkvz[(long)tg*3072 + 2048 + h*64 + v];
        float val = acc[nt][r]*scale*(1.f+nw[h*64+v])*siluf(z);
        obuf[(long)tg*1024 + h*64 + v] = (f16)val;
      }
    }
  }
}

__global__ __launch_bounds__(256)
void fin_kernel(const float* __restrict__ x2, const float* __restrict__ eo2,
                const float* __restrict__ sh, float* __restrict__ outx)
{
  long idx = (long)blockIdx.x*256 + threadIdx.x;
  outx[idx] = x2[idx] + eo2[idx] + eo2[idx + 2097152] + sh[idx];
}

// ---------------------------------------------------------------------------
extern "C" void kernel_launch(void* const* d_in, const int* in_sizes, int n_in,
                              void* d_out, int out_size, void* d_ws, size_t ws_size,
                              hipStream_t stream)
{
  (void)in_sizes; (void)n_in; (void)out_size; (void)ws_size;
  const float* x      = (const float*)d_in[0];
  const float* state  = (const float*)d_in[1];
  const float* cstate = (const float*)d_in[2];
  const float* w_qkv  = (const float*)d_in[3];
  const float* w_z    = (const float*)d_in[4];
  const float* w_a    = (const float*)d_in[5];
  const float* w_b    = (const float*)d_in[6];
  const float* convw  = (const float*)d_in[7];
  const float* dtb    = (const float*)d_in[8];
  const float* alog   = (const float*)d_in[9];
  const float* normw  = (const float*)d_in[10];
  const float* w_op   = (const float*)d_in[11];
  const float* rw     = (const float*)d_in[12];
  const float* w_gu   = (const float*)d_in[13];
  const float* w_dn   = (const float*)d_in[14];
  const float* w_sg   = (const float*)d_in[15];
  const float* w_su   = (const float*)d_in[16];
  const float* w_sd   = (const float*)d_in[17];
  const float* w_seg  = (const float*)d_in[18];
  const float* anw    = (const float*)d_in[19];
  const float* fnw    = (const float*)d_in[20];

  char* ws = (char*)d_ws;
  size_t off = 0;
  auto alloc = [&](size_t bytes)->char*{
    char* p = ws + off; off += (bytes + 255) & ~(size_t)255; return p;
  };
  f16*  wTqkvz = (f16*)alloc((size_t)3072*1024*2);
  f16*  wTop   = (f16*)alloc((size_t)1024*1024*2);
  f16*  wTsgu  = (f16*)alloc((size_t)2048*1024*2);
  f16*  wTsd   = (f16*)alloc((size_t)1024*1024*2);
  f16*  wGUc   = (f16*)alloc((size_t)8*1024*1024*2);
  f16*  wDNc   = (f16*)alloc((size_t)8*1024*512*2);
  f16*  hbuf   = (f16*)alloc((size_t)2048*1024*2);
  f16*  qkvzh  = (f16*)alloc((size_t)2048*3072*2);
  f16*  qn     = (f16*)alloc((size_t)2048*512*2);
  f16*  kn     = (f16*)alloc((size_t)2048*512*2);
  f16*  vb     = (f16*)alloc((size_t)2048*1024*2);
  float* gg    = (float*)alloc((size_t)2048*16*4);
  float* bbuf  = (float*)alloc((size_t)2048*16*4);
  f16*  U0     = (f16*)alloc((size_t)512*4096*2);
  f16*  WbB    = (f16*)alloc((size_t)512*4096*2);
  f16*  MT     = (f16*)alloc((size_t)512*4096*2);
  f16*  NT     = (f16*)alloc((size_t)512*4096*2);
  f16*  SS     = (f16*)alloc((size_t)512*4096*2);
  float* x2    = (float*)alloc((size_t)2048*1024*4);
  f16*  hfb    = (f16*)alloc((size_t)2048*1024*2);
  int*  cnt    = (int*)alloc(256);
  int*  etok   = (int*)alloc((size_t)8*2048*4);
  int*  eslot  = (int*)alloc((size_t)8*2048*4);
  float* ew    = (float*)alloc((size_t)8*2048*4);
  float* sigb  = (float*)alloc((size_t)2048*4);
  float4* tkbuf= (float4*)alloc((size_t)2048*16);
  float* eo2   = (float*)alloc((size_t)2*2048*1024*4);
  f16*  sactb  = (f16*)alloc((size_t)2048*1024*2);
  float* shb   = (float*)alloc((size_t)2048*1024*4);
  f16*  obuf  = hbuf;
  f16*  actb  = (f16*)U0;    // 16MB: U0+WbB+MT+NT (all dead before GUF)

  float* out_x = (float*)d_out;
  float* out_state = out_x + 2097152;
  float* out_conv = out_state + 65536;

  prep_kernel<<<10240, 256, 0, stream>>>(w_qkv, w_z, w_op, w_sg, w_su, w_sd, w_gu, w_dn,
                                         wTqkvz, wTop, wTsgu, wTsd, wGUc, wDNc);
  rms1<<<2048, 256, 0, stream>>>(x, anw, hbuf);
  gemm_k<GM_PLAIN16><<<dim3(24,16,1), 256, 0, stream>>>(hbuf, 0, wTqkvz, 0, 1024, 1024, 1024,
        nullptr, qkvzh, 3072, 0, nullptr, nullptr, nullptr, nullptr, nullptr, nullptr);
  ab_kernel<<<2048, 256, 0, stream>>>(hbuf, w_a, w_b, dtb, alog, gg, bbuf);
  conv_kernel<<<dim3(8,2048), 256, 0, stream>>>(qkvzh, cstate, convw, qn, kn, vb, out_conv);
  scan_pre<<<512, 256, 0, stream>>>(kn, vb, gg, bbuf, U0, WbB, MT, NT);
  scan_seq<<<64, 256, 0, stream>>>(state, MT, NT, SS, out_state);
  scan_out<<<512, 256, 0, stream>>>(qn, kn, gg, U0, WbB, SS, qkvzh, normw, obuf);
  gemm_k<GM_ADDX><<<dim3(8,16,1), 256, 0, stream>>>(obuf, 0, wTop, 0, 1024, 1024, 1024,
        x2, nullptr, 1024, 0, x, nullptr, nullptr, nullptr, nullptr, nullptr);
  rms2<<<2048, 256, 0, stream>>>(x2, fnw, rw, w_seg, hfb, tkbuf, sigb);
  route_build<<<1, 1024, 0, stream>>>(tkbuf, cnt, etok, eslot, ew);
  gemm_k<GM_GUF><<<dim3(8,16,8), 256, 0, stream>>>(hfb, 0, wGUc, (long)1024*1024, 1024, 1024, 1024,
        nullptr, actb, 512, (long)2048*512, nullptr, etok, cnt, nullptr, nullptr, nullptr);
  gemm_k<GM_DOWN><<<dim3(8,16,8), 256, 0, stream>>>(actb, (long)2048*512, wDNc, (long)1024*512,
        512, 512, 512,
        eo2, nullptr, 1024, 0, nullptr, etok, cnt, eslot, ew, nullptr);
  gemm_k<GM_SGUF><<<dim3(16,16,1), 256, 0, stream>>>(hfb, 0, wTsgu, 0, 1024, 1024, 1024,
        nullptr, sactb, 1024, 0, nullptr, nullptr, nullptr, nullptr, nullptr, nullptr);
  gemm_k<GM_SHD><<<dim3(8,16,1), 256, 0, stream>>>(sactb, 0, wTsd, 0, 1024, 1024, 1024,
        shb, nullptr, 1024, 0, nullptr, nullptr, nullptr, nullptr, nullptr, sigb);
  fin_kernel<<<8192, 256, 0, stream>>>(x2, eo2, shb, out_x);
}